// Round 5
// baseline (780.423 us; speedup 1.0000x reference)
//
#include <hip/hip_runtime.h>
#include <math.h>

#define BTOK 16384
#define DDIM 1024
#define HDIM 4096
#define NEXP 8
#define MAXT1 72    // gemm1 m-tiles (BM=256): <= 64 + 8 partials
#define MAXT2 96    // gemm2 m-tiles (BM=192): <= 93, padded to mult of 8

typedef float f32x4 __attribute__((ext_vector_type(4)));
typedef short short8 __attribute__((ext_vector_type(8)));

__device__ __forceinline__ unsigned int bf16r(float f) {
  unsigned int u = __float_as_uint(f);
  return (u + 0x7fffu + ((u >> 16) & 1u)) >> 16;  // RTN-even
}
__device__ __forceinline__ unsigned int pack2(float a, float b) {
  return bf16r(a) | (bf16r(b) << 16);
}
// tanh-GELU via exp: x*(1 - 1/(1+e^{2t})), t = sqrt(2/pi)(x+0.044715x^3)
__device__ __forceinline__ float gelu_fast(float x) {
  float t = 0.7978845608028654f * x * (1.0f + 0.044715f * x * x);
  float e = __expf(2.0f * t);
  return x * (1.0f - __builtin_amdgcn_rcpf(e + 1.0f));
}
// async global->LDS, 16B per lane; LDS dest must be uniform base + lane*16
__device__ __forceinline__ void gload16(const void* g, void* l) {
  __builtin_amdgcn_global_load_lds(
      (const __attribute__((address_space(1))) unsigned int*)g,
      (__attribute__((address_space(3))) unsigned int*)l, 16, 0, 0);
}

#define MFMA16(a, b, c) __builtin_amdgcn_mfma_f32_16x16x32_bf16((a), (b), (c), 0, 0, 0)

// ---------------- gating: fp64 logits, softmax, argmax; also emits x in bf16 ----------------
__global__ __launch_bounds__(256) void gate_kernel(
    const float* __restrict__ x, const float* __restrict__ Wg,
    float* __restrict__ gate_out, float* __restrict__ texp_out,
    float* __restrict__ tscore, int* __restrict__ expert_ws,
    unsigned short* __restrict__ xbf) {
  int wid = threadIdx.x >> 6, lane = threadIdx.x & 63;
  int b = blockIdx.x * 4 + wid;
  const float* xr = x + (size_t)b * DDIM;
  unsigned short* xbr = xbf + (size_t)b * DDIM;
  double acc[8];
#pragma unroll
  for (int e = 0; e < 8; ++e) acc[e] = 0.0;
#pragma unroll
  for (int i = 0; i < 4; ++i) {
    int d0 = (i * 64 + lane) * 4;
    float4 v = *(const float4*)(xr + d0);
    uint2 o;
    o.x = pack2(v.x, v.y);
    o.y = pack2(v.z, v.w);
    *(uint2*)(xbr + d0) = o;  // fused x -> bf16 conversion
    const float4* wp = (const float4*)(Wg + (size_t)d0 * 8);
    float xs[4] = {v.x, v.y, v.z, v.w};
#pragma unroll
    for (int j = 0; j < 4; ++j) {
      float4 w0 = wp[2 * j], w1 = wp[2 * j + 1];
      double xv = (double)xs[j];
      acc[0] += xv * (double)w0.x;
      acc[1] += xv * (double)w0.y;
      acc[2] += xv * (double)w0.z;
      acc[3] += xv * (double)w0.w;
      acc[4] += xv * (double)w1.x;
      acc[5] += xv * (double)w1.y;
      acc[6] += xv * (double)w1.z;
      acc[7] += xv * (double)w1.w;
    }
  }
#pragma unroll
  for (int off = 32; off > 0; off >>= 1) {
#pragma unroll
    for (int e = 0; e < 8; ++e) acc[e] += __shfl_down(acc[e], off, 64);
  }
  if (lane == 0) {
    double mx = acc[0];
#pragma unroll
    for (int e = 1; e < 8; ++e) mx = acc[e] > mx ? acc[e] : mx;
    double ex[8], s = 0.0;
#pragma unroll
    for (int e = 0; e < 8; ++e) { ex[e] = exp(acc[e] - mx); s += ex[e]; }
    int best = 0;
#pragma unroll
    for (int e = 1; e < 8; ++e) if (acc[e] > acc[best]) best = e;  // first-max
    double inv = 1.0 / s;
#pragma unroll
    for (int e = 0; e < 8; ++e) gate_out[(size_t)b * 8 + e] = (float)(ex[e] * inv);
    texp_out[b] = (float)best;
    tscore[b] = (float)(ex[best] * inv);
    expert_ws[b] = best;
  }
}

// ---------------- plan: ballot histogram + offsets + tile worklists (1 block) ----------------
__global__ __launch_bounds__(1024) void plan_kernel(
    const int* __restrict__ expert_ws, int* __restrict__ counts,
    int* __restrict__ offsets, int* __restrict__ cursors,
    int* __restrict__ tile1_e, int* __restrict__ tile1_ms, int* __restrict__ total_tiles1,
    int* __restrict__ tile2_e, int* __restrict__ tile2_ms, int* __restrict__ total_tiles2,
    float* __restrict__ dens_out) {
  __shared__ int wcnt[16][8];
  __shared__ int tot[8];
  int tid = threadIdx.x, lane = tid & 63, wid = tid >> 6;
  int cnt[8];
#pragma unroll
  for (int e = 0; e < 8; ++e) cnt[e] = 0;
  for (int i = 0; i < 16; ++i) {
    int e = expert_ws[wid * 1024 + i * 64 + lane];
#pragma unroll
    for (int ee = 0; ee < 8; ++ee) {
      unsigned long long m = __ballot(e == ee);
      cnt[ee] += __popcll(m);
    }
  }
  if (lane == 0) {
#pragma unroll
    for (int e = 0; e < 8; ++e) wcnt[wid][e] = cnt[e];
  }
  __syncthreads();
  if (tid < 8) {
    int s = 0;
    for (int w = 0; w < 16; ++w) s += wcnt[w][tid];
    tot[tid] = s;
    counts[tid] = s;
  }
  __syncthreads();
  if (tid == 0) {
    int off = 0, t1 = 0, t2 = 0;
    for (int e = 0; e < NEXP; ++e) {
      int c = tot[e];
      offsets[e] = off;
      cursors[e] = off;
      dens_out[e] = (float)c / (float)BTOK;
      for (int ms = 0; ms < c; ms += 256) { tile1_e[t1] = e; tile1_ms[t1] = ms; ++t1; }
      for (int ms = 0; ms < c; ms += 192) { tile2_e[t2] = e; tile2_ms[t2] = ms; ++t2; }
      off += c;
    }
    offsets[NEXP] = off;
    *total_tiles1 = t1;
    *total_tiles2 = t2;
  }
}

// ---------------- scatter: block-aggregated ranks, 8 atomics per block ----------------
__global__ __launch_bounds__(256) void scatter_kernel(
    const int* __restrict__ expert_ws, int* __restrict__ cursors,
    int* __restrict__ token_list) {
  __shared__ int wbase[4][8];
  __shared__ int bbase[8];
  int tid = threadIdx.x, lane = tid & 63, wid = tid >> 6;
  int b = blockIdx.x * 256 + tid;
  int e = expert_ws[b];
  unsigned long long mymask = 0;
  int wc[8];
#pragma unroll
  for (int ee = 0; ee < 8; ++ee) {
    unsigned long long m = __ballot(e == ee);
    wc[ee] = __popcll(m);
    if (ee == e) mymask = m;
  }
  int rank = __popcll(mymask & ((1ull << lane) - 1ull));
  if (lane == 0) {
#pragma unroll
    for (int ee = 0; ee < 8; ++ee) wbase[wid][ee] = wc[ee];
  }
  __syncthreads();
  if (tid < 8) {
    int s0 = wbase[0][tid], s1 = wbase[1][tid], s2 = wbase[2][tid], s3 = wbase[3][tid];
    int t = s0 + s1 + s2 + s3;
    bbase[tid] = atomicAdd(&cursors[tid], t);
    wbase[0][tid] = 0;
    wbase[1][tid] = s0;
    wbase[2][tid] = s0 + s1;
    wbase[3][tid] = s0 + s1 + s2;
  }
  __syncthreads();
  token_list[bbase[e] + wbase[wid][e] + rank] = b;
}

// ---------------- transpose + convert: in[z][R][C] fp32 -> out[z][C][R] bf16 ----------------
__global__ __launch_bounds__(256) void transpose_cvt_kernel(
    const float* __restrict__ in, unsigned short* __restrict__ out, int R, int C) {
  __shared__ unsigned short tT[64 * 68];  // [col][row^swz], pad 68
  const float* ine = in + (size_t)blockIdx.z * R * C;
  unsigned short* oute = out + (size_t)blockIdx.z * R * C;
  int r0 = blockIdx.y * 64, c0 = blockIdx.x * 64;
  int tid = threadIdx.x;
#pragma unroll
  for (int l = 0; l < 4; ++l) {
    int f = tid + 256 * l;           // 0..1023
    int r = f >> 4, c4 = f & 15;     // row, float4-col
    float4 v = *(const float4*)(ine + (size_t)(r0 + r) * C + c0 + c4 * 4);
#pragma unroll
    for (int i = 0; i < 4; ++i) {
      int cc = 4 * c4 + i;
      int s = ((cc >> 4) & 3) << 2;
      float val = i == 0 ? v.x : (i == 1 ? v.y : (i == 2 ? v.z : v.w));
      tT[cc * 68 + (r ^ s)] = (unsigned short)bf16r(val);
    }
  }
  __syncthreads();
#pragma unroll
  for (int l = 0; l < 4; ++l) {
    int f = tid + 256 * l;           // 0..1023
    int oc = f >> 4, h4 = f & 15;    // out-row (=col), 4-row chunk
    int s = ((oc >> 4) & 3) << 2;
    uint2 o = *(const uint2*)(&tT[oc * 68 + ((4 * h4) ^ s)]);  // rows 4h4..4h4+3
    *(uint2*)(oute + (size_t)(c0 + oc) * R + r0 + 4 * h4) = o;
  }
}

// ---------------- GEMM1: 256x256 tile, BK=64, SINGLE barrier per K-tile ----------------
// R4 post-mortem: the per-phase double-barrier lockstep globally serialized the
// LDS-read windows and MFMA windows (27% MfmaUtil == read/(read+mfma) exactly).
// New structure: stage ENTIRE next K-tile into nb at tile top (8 gloads, full
// ~1000cy tile to land so vmcnt(0)@end is ~free), then straight-line 24 ds_read +
// 64 MFMA (4-cluster register reuse) with NO inline waits: the compiler emits
// counted lgkmcnt interleave (m97 evidence) and wave skew overlaps the pipes.
// Safety of single barrier: every ds_read retires before barrier (consumed by a
// pre-barrier MFMA); stages only target nb; vmcnt(0)+barrier orders them before
// kt+1's reads; post-barrier restaging of old-cb is safe (all reads done).
__global__ __launch_bounds__(512, 1) void gemm1_kernel(
    const unsigned short* __restrict__ xbf, const unsigned short* __restrict__ W1t,
    const float* __restrict__ b1, const int* __restrict__ token_list,
    const int* __restrict__ offsets, const int* __restrict__ tile1_e,
    const int* __restrict__ tile1_ms, const int* __restrict__ total_tiles1,
    unsigned short* __restrict__ hbuf) {
  __shared__ __align__(16) unsigned short lds[65536];  // 2 buf x (A 16384 + B 16384 shorts)

  int bx = blockIdx.x;
  int t = (bx & 7) * 9 + (bx >> 3);  // XCD swizzle, 72 = 8*9 (bijective)
  if (t >= *total_tiles1) return;
  int e = tile1_e[t], mstart = tile1_ms[t];
  int base = offsets[e], endp = offsets[e + 1];
  int ntile = blockIdx.y;

  int tid = threadIdx.x;
  int lane = tid & 63, wid = tid >> 6;
  int wm = wid & 1, wn = wid >> 1;      // 2 x 4 waves, wave tile 128x64
  int quad = lane >> 4, l16 = lane & 15;

  int rr = tid >> 3;                    // 0..63
  int g = (tid & 7) ^ (rr & 7);         // staged global k-chunk; slot=tid&7
  int aoff[4];
#pragma unroll
  for (int j = 0; j < 4; ++j) {
    int p = base + mstart + 64 * j + rr;
    p = p < endp ? p : endp - 1;
    aoff[j] = token_list[p] * DDIM + g * 8;
  }
  int boff0 = e * (HDIM * DDIM) + (ntile * 256 + rr) * DDIM + g * 8;

  int swq0 = (quad ^ (l16 & 7)) * 8;        // k-chunks 0..3 (kk=0)
  int swq1 = ((4 + quad) ^ (l16 & 7)) * 8;  // k-chunks 4..7 (kk=1)

  f32x4 acc[8][4];
#pragma unroll
  for (int i = 0; i < 8; ++i)
#pragma unroll
    for (int j = 0; j < 4; ++j) acc[i][j] = (f32x4)0.0f;

  // stage one full 256x64 K-tile pair (A + B) into buffer bo: 8 gloads/thread
  auto stage_tile = [&](int ko, int bo) {
    unsigned short* LA = lds + bo + tid * 8;
    unsigned short* LB = lds + bo + 16384 + tid * 8;
#pragma unroll
    for (int j = 0; j < 4; ++j) {
      gload16(xbf + aoff[j] + ko, LA + j * 4096);
      gload16(W1t + boff0 + j * 64 * DDIM + ko, LB + j * 4096);
    }
  };

  // prologue: stage tile 0 into buf0, drain, sync
  stage_tile(0, 0);
  asm volatile("s_waitcnt vmcnt(0)");
  __builtin_amdgcn_sched_barrier(0);
  __builtin_amdgcn_s_barrier();
  __builtin_amdgcn_sched_barrier(0);

  const int NT = DDIM / 64;  // 16
  for (int kt = 0; kt < NT; ++kt) {
    int cb = (kt & 1) * 32768;
    int nb = cb ^ 32768;
    // stage next tile first: full tile duration to land
    if (kt + 1 < NT) stage_tile((kt + 1) * 64, nb);

    const unsigned short* Ab = lds + cb + (wm * 128 + l16) * 64;
    const unsigned short* Bb = lds + cb + 16384 + (wn * 64 + l16) * 64;
    short8 aev[4][2], aod[4][2], bl[2][2], bh[2][2];

    // C0: aev x bl -> acc[0..3][0..1]
#pragma unroll
    for (int fi = 0; fi < 4; ++fi) {
      aev[fi][0] = *(const short8*)(Ab + fi * 1024 + swq0);
      aev[fi][1] = *(const short8*)(Ab + fi * 1024 + swq1);
    }
#pragma unroll
    for (int fj = 0; fj < 2; ++fj) {
      bl[fj][0] = *(const short8*)(Bb + fj * 1024 + swq0);
      bl[fj][1] = *(const short8*)(Bb + fj * 1024 + swq1);
    }
#pragma unroll
    for (int fi = 0; fi < 4; ++fi)
#pragma unroll
      for (int fj = 0; fj < 2; ++fj) {
        acc[fi][fj] = MFMA16(aev[fi][0], bl[fj][0], acc[fi][fj]);
        acc[fi][fj] = MFMA16(aev[fi][1], bl[fj][1], acc[fi][fj]);
      }
    // C1: aod x bl -> acc[4..7][0..1]
#pragma unroll
    for (int fi = 0; fi < 4; ++fi) {
      aod[fi][0] = *(const short8*)(Ab + 4096 + fi * 1024 + swq0);
      aod[fi][1] = *(const short8*)(Ab + 4096 + fi * 1024 + swq1);
    }
#pragma unroll
    for (int fi = 0; fi < 4; ++fi)
#pragma unroll
      for (int fj = 0; fj < 2; ++fj) {
        acc[4 + fi][fj] = MFMA16(aod[fi][0], bl[fj][0], acc[4 + fi][fj]);
        acc[4 + fi][fj] = MFMA16(aod[fi][1], bl[fj][1], acc[4 + fi][fj]);
      }
    // C2: aev x bh -> acc[0..3][2..3]
#pragma unroll
    for (int fj = 0; fj < 2; ++fj) {
      bh[fj][0] = *(const short8*)(Bb + 2048 + fj * 1024 + swq0);
      bh[fj][1] = *(const short8*)(Bb + 2048 + fj * 1024 + swq1);
    }
#pragma unroll
    for (int fi = 0; fi < 4; ++fi)
#pragma unroll
      for (int fj = 0; fj < 2; ++fj) {
        acc[fi][2 + fj] = MFMA16(aev[fi][0], bh[fj][0], acc[fi][2 + fj]);
        acc[fi][2 + fj] = MFMA16(aev[fi][1], bh[fj][1], acc[fi][2 + fj]);
      }
    // C3: aod x bh -> acc[4..7][2..3]
#pragma unroll
    for (int fi = 0; fi < 4; ++fi)
#pragma unroll
      for (int fj = 0; fj < 2; ++fj) {
        acc[4 + fi][2 + fj] = MFMA16(aod[fi][0], bh[fj][0], acc[4 + fi][2 + fj]);
        acc[4 + fi][2 + fj] = MFMA16(aod[fi][1], bh[fj][1], acc[4 + fi][2 + fj]);
      }

    // single sync point per K-tile: next tile's stages landed, all reads retired
    asm volatile("s_waitcnt vmcnt(0)");
    __builtin_amdgcn_sched_barrier(0);
    __builtin_amdgcn_s_barrier();
    __builtin_amdgcn_sched_barrier(0);
  }

  const float* b1e = b1 + (size_t)e * HDIM + ntile * 256;
#pragma unroll
  for (int hm = 0; hm < 2; ++hm) {
#pragma unroll
    for (int fi = 0; fi < 4; ++fi) {
#pragma unroll
      for (int rg = 0; rg < 4; ++rg) {
        int row = wm * 128 + hm * 64 + fi * 16 + quad * 4 + rg;
        int p = base + mstart + row;
        if (p < endp) {
          size_t ob = (size_t)p * HDIM + ntile * 256;
#pragma unroll
          for (int fj = 0; fj < 4; ++fj) {
            int col = wn * 64 + fj * 16 + l16;
            float v = acc[hm * 4 + fi][fj][rg] + b1e[col];
            hbuf[ob + col] = (unsigned short)bf16r(gelu_fast(v));
          }
        }
      }
    }
  }
}

// ---------------- GEMM2: out[tok] = (h @ W2[e] + b2[e]) * top_score ----------------
// BM=192 (wave tile 96x64, 6x4 frags): grid = 96*8 = 768 = exactly 3 blocks/CU.
__global__ __launch_bounds__(256, 3) void gemm2_kernel(
    const unsigned short* __restrict__ hbuf, const unsigned short* __restrict__ W2t,
    const float* __restrict__ b2, const int* __restrict__ token_list,
    const int* __restrict__ offsets, const int* __restrict__ tile2_e,
    const int* __restrict__ tile2_ms, const int* __restrict__ total_tiles2,
    const float* __restrict__ tscore, float* __restrict__ out) {
  __shared__ __align__(16) unsigned short ldsA[192 * 32];
  __shared__ __align__(16) unsigned short ldsB[128 * 32];

  int bx = blockIdx.x;
  int t = (bx & 7) * 12 + (bx >> 3);  // XCD swizzle: 96 = 8*12
  if (t >= *total_tiles2) return;
  int e = tile2_e[t], mstart = tile2_ms[t];
  int base = offsets[e], endp = offsets[e + 1];
  int ntile = blockIdx.y;

  int tid = threadIdx.x;
  int lane = tid & 63, wid = tid >> 6;
  int wr = wid & 1, wc = wid >> 1;
  int quad = lane >> 4, l16 = lane & 15;

  int rowA = tid >> 2, slot = tid & 3;
  int sw = slot ^ (rowA & 3) ^ ((rowA >> 2) & 3);
  int p0 = base + mstart + rowA;
  int pe0 = p0 < endp ? p0 : endp - 1;
  int pe1 = p0 + 64 < endp ? p0 + 64 : endp - 1;
  int pe2 = p0 + 128 < endp ? p0 + 128 : endp - 1;
  int offA0 = pe0 * HDIM + sw * 8;
  int offA1 = pe1 * HDIM + sw * 8;
  int offA2 = pe2 * HDIM + sw * 8;
  int offB0 = e * (HDIM * DDIM) + (ntile * 128 + rowA) * HDIM + sw * 8;
  int offB1 = offB0 + 64 * HDIM;
  unsigned short* la0 = &ldsA[tid * 8];
  unsigned short* la1 = &ldsA[2048 + tid * 8];
  unsigned short* la2 = &ldsA[4096 + tid * 8];
  unsigned short* lb0 = &ldsB[tid * 8];
  unsigned short* lb1 = &ldsB[2048 + tid * 8];

  int swq = (quad ^ (l16 & 3) ^ ((l16 >> 2) & 3)) * 8;

  f32x4 acc[6][4];
#pragma unroll
  for (int i = 0; i < 6; ++i)
#pragma unroll
    for (int j = 0; j < 4; ++j) acc[i][j] = (f32x4)0.0f;

  for (int k0 = 0; k0 < HDIM; k0 += 32) {
    gload16(hbuf + offA0 + k0, la0);
    gload16(hbuf + offA1 + k0, la1);
    gload16(hbuf + offA2 + k0, la2);
    gload16(W2t + offB0 + k0, lb0);
    gload16(W2t + offB1 + k0, lb1);
    __syncthreads();
    short8 af[6], bfr[4];
#pragma unroll
    for (int i = 0; i < 6; ++i)
      af[i] = *(const short8*)(&ldsA[(wr * 96 + 16 * i + l16) * 32 + swq]);
#pragma unroll
    for (int j = 0; j < 4; ++j)
      bfr[j] = *(const short8*)(&ldsB[(wc * 64 + 16 * j + l16) * 32 + swq]);
#pragma unroll
    for (int i = 0; i < 6; ++i)
#pragma unroll
      for (int j = 0; j < 4; ++j)
        acc[i][j] = MFMA16(af[i], bfr[j], acc[i][j]);
    __syncthreads();
  }

  const float* b2e = b2 + (size_t)e * DDIM + ntile * 128;
#pragma unroll
  for (int i = 0; i < 6; ++i) {
#pragma unroll
    for (int r = 0; r < 4; ++r) {
      int row = wr * 96 + 16 * i + quad * 4 + r;
      int p = base + mstart + row;
      if (p < endp) {
        int tok = token_list[p];
        float ts = tscore[tok];
        size_t ob = (size_t)tok * DDIM + ntile * 128;
#pragma unroll
        for (int j = 0; j < 4; ++j) {
          int col = wc * 64 + 16 * j + l16;
          out[ob + col] = (acc[i][j][r] + b2e[col]) * ts;
        }
      }
    }
  }
}

extern "C" void kernel_launch(void* const* d_in, const int* in_sizes, int n_in,
                              void* d_out, int out_size, void* d_ws, size_t ws_size,
                              hipStream_t stream) {
  const float* x  = (const float*)d_in[0];
  const float* Wg = (const float*)d_in[1];
  const float* W1 = (const float*)d_in[2];
  const float* b1 = (const float*)d_in[3];
  const float* W2 = (const float*)d_in[4];
  const float* b2 = (const float*)d_in[5];

  float* out_main = (float*)d_out;
  float* gate_out = out_main + (size_t)BTOK * DDIM;
  float* texp_out = gate_out + (size_t)BTOK * NEXP;
  float* dens_out = texp_out + BTOK;

  char* w = (char*)d_ws;
  size_t off = 0;
  unsigned short* hbuf = (unsigned short*)(w + off); off += (size_t)BTOK * HDIM * 2;  // 134 MB
  unsigned short* xbf  = (unsigned short*)(w + off); off += (size_t)BTOK * DDIM * 2;  // 33.5 MB
  unsigned short* W1t  = (unsigned short*)(w + off); off += (size_t)NEXP * DDIM * HDIM * 2;  // 67 MB
  unsigned short* W2t  = (unsigned short*)(w + off); off += (size_t)NEXP * DDIM * HDIM * 2;  // 67 MB
  float* tscore     = (float*)(w + off); off += (size_t)BTOK * 4;
  int* expert_ws    = (int*)(w + off);   off += (size_t)BTOK * 4;
  int* token_list   = (int*)(w + off);   off += (size_t)BTOK * 4;
  int* counts       = (int*)(w + off);   off += 256;
  int* offsets      = (int*)(w + off);   off += 256;
  int* cursors      = (int*)(w + off);   off += 256;
  int* tile1_e      = (int*)(w + off);   off += 512;
  int* tile1_ms     = (int*)(w + off);   off += 512;
  int* total_tiles1 = (int*)(w + off);   off += 256;
  int* tile2_e      = (int*)(w + off);   off += 512;
  int* tile2_ms     = (int*)(w + off);   off += 512;
  int* total_tiles2 = (int*)(w + off);   off += 256;

  hipLaunchKernelGGL(gate_kernel, dim3(BTOK / 4), dim3(256), 0, stream,
                     x, Wg, gate_out, texp_out, tscore, expert_ws, xbf);
  hipLaunchKernelGGL(plan_kernel, dim3(1), dim3(1024), 0, stream,
                     expert_ws, counts, offsets, cursors,
                     tile1_e, tile1_ms, total_tiles1,
                     tile2_e, tile2_ms, total_tiles2, dens_out);
  hipLaunchKernelGGL(scatter_kernel, dim3(BTOK / 256), dim3(256), 0, stream,
                     expert_ws, cursors, token_list);
  hipLaunchKernelGGL(transpose_cvt_kernel, dim3(HDIM / 64, DDIM / 64, NEXP), dim3(256), 0, stream,
                     W1, W1t, DDIM, HDIM);
  hipLaunchKernelGGL(transpose_cvt_kernel, dim3(DDIM / 64, HDIM / 64, NEXP), dim3(256), 0, stream,
                     W2, W2t, HDIM, DDIM);
  hipLaunchKernelGGL(gemm1_kernel, dim3(MAXT1, HDIM / 256), dim3(512), 0, stream,
                     xbf, W1t, b1, token_list, offsets, tile1_e, tile1_ms, total_tiles1, hbuf);
  hipLaunchKernelGGL(gemm2_kernel, dim3(MAXT2, DDIM / 128), dim3(256), 0, stream,
                     hbuf, W2t, b2, token_list, offsets, tile2_e, tile2_ms, total_tiles2, tscore, out_main);
}